// Round 9
// baseline (304.384 us; speedup 1.0000x reference)
//
#include <hip/hip_runtime.h>
#include <hip/hip_bf16.h>
#include <hip/hip_cooperative_groups.h>

namespace cg = cooperative_groups;

#define T_TOKENS 2048
#define DMODEL   1024
#define NEXPERT  16
#define TOPK     2
#define NASSIGN  (T_TOKENS * TOPK)   // 4096

#define GBM 64
#define GBN 128
#define GBK 128
#define NBLK 512                     // cooperative grid: 2/CU (<=3/CU LDS bound)

typedef __attribute__((ext_vector_type(8))) short  short8;
typedef __attribute__((ext_vector_type(4))) float  floatx4;
typedef __attribute__((ext_vector_type(8))) unsigned short ushort8;
typedef __attribute__((ext_vector_type(4))) unsigned short usv4;

__device__ __forceinline__ unsigned short f2bf(float f) {
    unsigned u = __builtin_bit_cast(unsigned, f);
    u += 0x7fff + ((u >> 16) & 1);   // RNE truncate to bf16
    return (unsigned short)(u >> 16);
}

// async global->LDS, 16 B per lane; LDS dest = wave-uniform base + lane*16
__device__ __forceinline__ void g2l16(const void* g, void* l) {
    __builtin_amdgcn_global_load_lds(
        (__attribute__((address_space(1))) void*)g,
        (__attribute__((address_space(3))) void*)l, 16, 0, 0);
}

// ---------------------------------------------------------------------------
// Fused cooperative kernel: 512 blocks x 256 threads, 2 grid.sync()s.
//  Phase 0: block 0 routing; all blocks: x->bf16 (4 rows each) and
//           W [e][k][n] f32 -> wbf [e][n][k] bf16 (8 64x64 tiles each)
//  Phase 1: grouped GEMM, persistent loop over 1024 items (2/block),
//           64x128 tile, BK=128, g2l staging + XOR chunk swizzle
//  Phase 2: combine out[t] = eo[2t] + eo[2t+1]  (4 rows/block)
// ---------------------------------------------------------------------------
__global__ __launch_bounds__(256) void fused_moe(
    const float* __restrict__ x,       // [T][D] f32
    const int*   __restrict__ gidx,    // [T*TOPK]
    const float* __restrict__ W,       // [E][D][D] f32 (k-major, n contig)
    const float* __restrict__ bias,    // [E][D]
    const float* __restrict__ score,   // [T*TOPK]
    unsigned short* __restrict__ xbf,  // ws: [T][D] bf16
    unsigned short* __restrict__ wbf,  // ws: [E][n][k] bf16
    int* __restrict__ counts, int* __restrict__ offsets, int* __restrict__ list,
    float* __restrict__ eo,            // ws: [NASSIGN][D]
    float* __restrict__ out)           // [T][D]
{
    __shared__ __align__(16) unsigned short sA[GBM][GBK];   // 16 KB
    __shared__ __align__(16) unsigned short sB[GBN][GBK];   // 32 KB
    __shared__ int rs[32];                                  // routing scratch

    const int b = blockIdx.x;
    const int t = threadIdx.x;
    cg::grid_group grid = cg::this_grid();

    // ================= Phase 0 =================
    if (b == 0) {
        int* s_cnt = rs;
        int* s_off = rs + NEXPERT;
        if (t < NEXPERT) s_cnt[t] = 0;
        __syncthreads();
        for (int a = t; a < NASSIGN; a += 256)
            atomicAdd(&s_cnt[gidx[a]], 1);
        __syncthreads();
        if (t == 0) {
            int run = 0;
            for (int e = 0; e < NEXPERT; e++) { s_off[e] = run; run += s_cnt[e]; }
        }
        __syncthreads();
        if (t < NEXPERT) {
            counts[t]  = s_cnt[t];
            offsets[t] = s_off[t];
            s_cnt[t]   = s_off[t];            // reuse as cursor
        }
        __syncthreads();
        for (int a = t; a < NASSIGN; a += 256) {
            int e = gidx[a];
            list[atomicAdd(&s_cnt[e], 1)] = a;
        }
    }

    // ---- x -> bf16: 4 rows per block
    #pragma unroll
    for (int r = 0; r < 4; r++) {
        const int row = b * 4 + r;
        const float4 v = ((const float4*)(x + (size_t)row * DMODEL))[t];
        usv4 c;
        c.x = f2bf(v.x); c.y = f2bf(v.y); c.z = f2bf(v.z); c.w = f2bf(v.w);
        ((usv4*)(xbf + (size_t)row * DMODEL))[t] = c;
    }

    // ---- W transpose: 8 64x64 tiles per block (4096 tiles total)
    {
        unsigned short (*sT)[72] = (unsigned short (*)[72])&sA[0][0];  // 9216 B
        const int ks = t >> 4;          // k sub-row in group of 16
        const int nq = (t & 15) * 4;    // 4-wide n quad
        const int nr = t >> 2, kc = t & 3;
        for (int i = 0; i < 8; i++) {
            const int idx = b * 8 + i;
            const int e  = idx >> 8;
            const int k0 = ((idx >> 4) & 15) * 64;
            const int n0 = (idx & 15) * 64;
            const float* srcbase = W + ((size_t)(e * DMODEL + k0 + ks)) * DMODEL + n0 + nq;
            __syncthreads();            // protect sT reuse across iterations
            #pragma unroll
            for (int c = 0; c < 4; c++) {
                const int k = c * 16 + ks;
                const float4 v = *(const float4*)(srcbase + (size_t)c * 16 * DMODEL);
                sT[nq + 0][k] = f2bf(v.x);
                sT[nq + 1][k] = f2bf(v.y);
                sT[nq + 2][k] = f2bf(v.z);
                sT[nq + 3][k] = f2bf(v.w);
            }
            __syncthreads();
            ushort8 v0 = *(const ushort8*)&sT[nr][kc * 16];
            ushort8 v1 = *(const ushort8*)&sT[nr][kc * 16 + 8];
            unsigned short* dst = wbf + (size_t)(e * DMODEL + n0 + nr) * DMODEL + k0 + kc * 16;
            *(ushort8*)dst       = v0;
            *(ushort8*)(dst + 8) = v1;
        }
    }

    grid.sync();

    // ================= Phase 1: grouped GEMM =================
    {
        const int rsub = t >> 4;        // 0..15 staging row in 16-row group
        const int pch  = t & 15;        // physical 16B chunk
        const int wave = t >> 6;
        const int lane = t & 63;
        const int wn   = wave * 32;
        const int fr   = lane & 15;
        const int quad = lane >> 4;
        char* lA = (char*)&sA[0][0] + t * 16;
        char* lB = (char*)&sB[0][0] + t * 16;

        for (int item = b; item < 1024; item += NBLK) {
            const int e  = item >> 6;
            const int mt = (item >> 3) & 7;
            const int nt = item & 7;
            const int cnt = counts[e];
            const int m0  = mt * GBM;
            if (m0 >= cnt) continue;
            const int n0  = nt * GBN;
            const int off = offsets[e];

            // A sources: rows c*16+rsub gathered via list
            const unsigned short* asrc[4];
            #pragma unroll
            for (int c = 0; c < 4; c++) {
                const int row = c * 16 + rsub;
                const int gm  = m0 + row;
                const int tok = (gm < cnt) ? (list[off + gm] >> 1) : 0;
                asrc[c] = xbf + (size_t)tok * DMODEL + (pch ^ (row & 15)) * 8;
            }
            // B sources: rows c*16+rsub of the n-tile
            const unsigned short* wbbase = wbf + (size_t)e * DMODEL * DMODEL;
            const unsigned short* bsrc[8];
            #pragma unroll
            for (int c = 0; c < 8; c++) {
                const int row = c * 16 + rsub;
                bsrc[c] = wbbase + (size_t)(n0 + row) * DMODEL + (pch ^ (row & 15)) * 8;
            }

            floatx4 acc[4][2] = {};

            for (int k0 = 0; k0 < DMODEL; k0 += GBK) {
                __syncthreads();        // protect LDS reuse (prev item / phase)
                #pragma unroll
                for (int c = 0; c < 4; c++)
                    g2l16(asrc[c] + k0, lA + c * 4096);
                #pragma unroll
                for (int c = 0; c < 8; c++)
                    g2l16(bsrc[c] + k0, lB + c * 4096);
                __syncthreads();        // vmcnt(0) drain before barrier

                #pragma unroll
                for (int kk = 0; kk < 4; kk++) {
                    const int cc = (kk * 4 + quad) ^ fr;   // swizzled chunk
                    short8 af[4], bf[2];
                    #pragma unroll
                    for (int mi = 0; mi < 4; mi++)
                        af[mi] = *(const short8*)&sA[mi * 16 + fr][cc * 8];
                    #pragma unroll
                    for (int ni = 0; ni < 2; ni++)
                        bf[ni] = *(const short8*)&sB[wn + ni * 16 + fr][cc * 8];
                    #pragma unroll
                    for (int mi = 0; mi < 4; mi++)
                        #pragma unroll
                        for (int ni = 0; ni < 2; ni++)
                            acc[mi][ni] = __builtin_amdgcn_mfma_f32_16x16x32_bf16(
                                af[mi], bf[ni], acc[mi][ni], 0, 0, 0);
                }
            }
            __syncthreads();

            // epilogue: C/D layout col = lane&15, row = quad*4 + r  [m89]
            const int colA = n0 + wn + fr;
            const int colB = colA + 16;
            const float bv0 = bias[e * DMODEL + colA];
            const float bv1 = bias[e * DMODEL + colB];
            #pragma unroll
            for (int mi = 0; mi < 4; mi++) {
                const int rb = mi * 16 + quad * 4;
                #pragma unroll
                for (int r = 0; r < 4; r++) {
                    const int gm = m0 + rb + r;
                    if (gm >= cnt) continue;
                    const int a = list[off + gm];
                    const float s = score[a];
                    float* row = eo + (size_t)a * DMODEL;
                    row[colA] = s * (acc[mi][0][r] + bv0);
                    row[colB] = s * (acc[mi][1][r] + bv1);
                }
            }
        }
    }

    grid.sync();

    // ================= Phase 2: combine =================
    #pragma unroll
    for (int r = 0; r < 4; r++) {
        const int tok = b * 4 + r;
        const float4 a = ((const float4*)(eo + (size_t)(2 * tok)     * DMODEL))[t];
        const float4 c = ((const float4*)(eo + (size_t)(2 * tok + 1) * DMODEL))[t];
        ((float4*)(out + (size_t)tok * DMODEL))[t] =
            make_float4(a.x + c.x, a.y + c.y, a.z + c.z, a.w + c.w);
    }
}

// ---------------------------------------------------------------------------
// Fallback (ws too small): routing + inline-conversion GEMM with atomics.
// ---------------------------------------------------------------------------
__global__ void build_routing(const int* __restrict__ gate_idx,
                              int* __restrict__ counts,
                              int* __restrict__ offsets,
                              int* __restrict__ list) {
    __shared__ int s_cnt[NEXPERT];
    __shared__ int s_off[NEXPERT];
    const int tid = threadIdx.x;
    if (tid < NEXPERT) s_cnt[tid] = 0;
    __syncthreads();
    for (int a = tid; a < NASSIGN; a += blockDim.x)
        atomicAdd(&s_cnt[gate_idx[a]], 1);
    __syncthreads();
    if (tid == 0) {
        int run = 0;
        for (int e = 0; e < NEXPERT; e++) { s_off[e] = run; run += s_cnt[e]; }
    }
    __syncthreads();
    if (tid < NEXPERT) {
        counts[tid]  = s_cnt[tid];
        offsets[tid] = s_off[tid];
        s_cnt[tid]   = s_off[tid];
    }
    __syncthreads();
    for (int a = tid; a < NASSIGN; a += blockDim.x) {
        int e = gate_idx[a];
        int pos = atomicAdd(&s_cnt[e], 1);
        list[pos] = a;
    }
}

#define LDSK 72
__global__ __launch_bounds__(256) void moe_gemm_inline(
    const float* __restrict__ x, const float* __restrict__ W,
    const float* __restrict__ bias, const float* __restrict__ score,
    const int* __restrict__ counts, const int* __restrict__ offsets,
    const int* __restrict__ list, float* __restrict__ dst)
{
    const int e   = blockIdx.z;
    const int cnt = counts[e];
    const int m0  = blockIdx.y * 64;
    if (m0 >= cnt) return;
    const int n0  = blockIdx.x * 64;
    const int off = offsets[e];

    __shared__ __align__(16) unsigned short sA[64][LDSK];
    __shared__ __align__(16) unsigned short sB[64][LDSK];

    const int tid = threadIdx.x;
    const int arow = tid >> 2, aq = tid & 3, acol = aq * 16;
    const bool avalid = (m0 + arow) < cnt;
    int atok = 0;
    if (avalid) atok = list[off + m0 + arow] >> 1;
    const float* xsrc = x + (size_t)atok * DMODEL + acol;

    const int bk = tid >> 2, bng = tid & 3, bn = bng * 16, rot = tid & 15;
    const float* wsrc = W + (size_t)(e * DMODEL + bk) * DMODEL + n0 + bn;

    const int wave = tid >> 6, lane = tid & 63;
    const int wn = wave * 16, fr = lane & 15, quad = lane >> 4;

    floatx4 acc[4] = {};

    for (int k0 = 0; k0 < DMODEL; k0 += 64) {
        {
            float4 v[4];
            if (avalid) {
                const float4* p = (const float4*)(xsrc + k0);
                v[0] = p[0]; v[1] = p[1]; v[2] = p[2]; v[3] = p[3];
            } else {
                v[0] = v[1] = v[2] = v[3] = make_float4(0.f, 0.f, 0.f, 0.f);
            }
            __align__(16) unsigned short cvt[16];
            #pragma unroll
            for (int i = 0; i < 4; i++) {
                cvt[4*i+0] = f2bf(v[i].x); cvt[4*i+1] = f2bf(v[i].y);
                cvt[4*i+2] = f2bf(v[i].z); cvt[4*i+3] = f2bf(v[i].w);
            }
            *(ushort8*)&sA[arow][acol]     = *(ushort8*)&cvt[0];
            *(ushort8*)&sA[arow][acol + 8] = *(ushort8*)&cvt[8];
        }
        {
            const float4* p = (const float4*)(wsrc + (size_t)k0 * DMODEL);
            float4 v[4];
            v[0] = p[0]; v[1] = p[1]; v[2] = p[2]; v[3] = p[3];
            unsigned short cvt[16];
            #pragma unroll
            for (int i = 0; i < 4; i++) {
                cvt[4*i+0] = f2bf(v[i].x); cvt[4*i+1] = f2bf(v[i].y);
                cvt[4*i+2] = f2bf(v[i].z); cvt[4*i+3] = f2bf(v[i].w);
            }
            #pragma unroll
            for (int i = 0; i < 16; i++) {
                int m = (i + rot) & 15;
                sB[bn + m][bk] = cvt[m];
            }
        }
        __syncthreads();
        #pragma unroll
        for (int kk = 0; kk < 2; kk++) {
            const int ko = kk * 32 + quad * 8;
            short8 af[4], bf;
            #pragma unroll
            for (int mi = 0; mi < 4; mi++)
                af[mi] = *(const short8*)&sA[mi * 16 + fr][ko];
            bf = *(const short8*)&sB[wn + fr][ko];
            #pragma unroll
            for (int mi = 0; mi < 4; mi++)
                acc[mi] = __builtin_amdgcn_mfma_f32_16x16x32_bf16(af[mi], bf, acc[mi], 0, 0, 0);
        }
        __syncthreads();
    }

    const int col = n0 + wn + fr;
    const float bv = bias[e * DMODEL + col];
    #pragma unroll
    for (int mi = 0; mi < 4; mi++) {
        const int rb = mi * 16 + quad * 4;
        #pragma unroll
        for (int r = 0; r < 4; r++) {
            const int gm = m0 + rb + r;
            if (gm >= cnt) continue;
            const int a = list[off + gm];
            atomicAdd(&dst[(size_t)(a >> 1) * DMODEL + col],
                      score[a] * (acc[mi][r] + bv));
        }
    }
}

extern "C" void kernel_launch(void* const* d_in, const int* in_sizes, int n_in,
                              void* d_out, int out_size, void* d_ws, size_t ws_size,
                              hipStream_t stream) {
    const float* x    = (const float*)d_in[0];   // [2048,1024] f32
    const int*   gidx = (const int*)d_in[1];     // [2048,2] int
    const float* gsc  = (const float*)d_in[2];   // [2048,2] f32
    const float* W    = (const float*)d_in[3];   // [16,1024,1024] f32
    const float* bias = (const float*)d_in[4];   // [16,1024] f32
    float* out = (float*)d_out;

    int* ws      = (int*)d_ws;
    int* counts  = ws;
    int* offsets = ws + 16;
    int* list    = ws + 32;

    const size_t eo_off  = 32 * 1024;
    const size_t eo_sz   = (size_t)NASSIGN * DMODEL * sizeof(float);               // 16 MB
    const size_t xbf_off = eo_off + eo_sz;
    const size_t xbf_sz  = (size_t)T_TOKENS * DMODEL * sizeof(unsigned short);     //  4 MB
    const size_t wbf_off = xbf_off + xbf_sz;
    const size_t wbf_sz  = (size_t)NEXPERT * DMODEL * DMODEL * sizeof(unsigned short); // 32 MB
    const size_t need_full = wbf_off + wbf_sz;

    float*          eo  = (float*)((char*)d_ws + eo_off);
    unsigned short* xbf = (unsigned short*)((char*)d_ws + xbf_off);
    unsigned short* wbf = (unsigned short*)((char*)d_ws + wbf_off);

    if (ws_size >= need_full) {
        void* args[] = { (void*)&x, (void*)&gidx, (void*)&W, (void*)&bias,
                         (void*)&gsc, (void*)&xbf, (void*)&wbf,
                         (void*)&counts, (void*)&offsets, (void*)&list,
                         (void*)&eo, (void*)&out };
        hipLaunchCooperativeKernel((void*)fused_moe, dim3(NBLK), dim3(256),
                                   args, 0, stream);
    } else {
        build_routing<<<1, 256, 0, stream>>>(gidx, counts, offsets, list);
        hipMemsetAsync(d_out, 0, (size_t)T_TOKENS * DMODEL * sizeof(float), stream);
        dim3 grid(DMODEL / 64, 512 / 64, NEXPERT);
        moe_gemm_inline<<<grid, 256, 0, stream>>>(x, W, bias, gsc,
                                                  counts, offsets, list, out);
    }
}

// Round 10
// 145.387 us; speedup vs baseline: 2.0936x; 2.0936x over previous
//
#include <hip/hip_runtime.h>
#include <hip/hip_bf16.h>

#define T_TOKENS 2048
#define DMODEL   1024
#define NEXPERT  16
#define TOPK     2
#define NASSIGN  (T_TOKENS * TOPK)   // 4096

#define GBM 64
#define GBN 128
#define GBK 64

typedef __attribute__((ext_vector_type(8))) short  short8;
typedef __attribute__((ext_vector_type(4))) float  floatx4;
typedef __attribute__((ext_vector_type(8))) unsigned short ushort8;
typedef __attribute__((ext_vector_type(4))) unsigned short usv4;

__device__ __forceinline__ unsigned short f2bf(float f) {
    unsigned u = __builtin_bit_cast(unsigned, f);
    u += 0x7fff + ((u >> 16) & 1);   // RNE truncate to bf16
    return (unsigned short)(u >> 16);
}
__device__ __forceinline__ float bf2f(unsigned short s) {
    return __builtin_bit_cast(float, (unsigned)s << 16);
}

// async global->LDS, 16 B per lane; LDS dest = wave-uniform base + lane*16
__device__ __forceinline__ void g2l16(const void* g, void* l) {
    __builtin_amdgcn_global_load_lds(
        (__attribute__((address_space(1))) void*)g,
        (__attribute__((address_space(3))) void*)l, 16, 0, 0);
}

// ---------------------------------------------------------------------------
// Fused prep kernel (3 independent jobs, selected by blockIdx.x):
//   block 0           : routing -> counts[16] | offsets[16] | list[4096]
//   blocks 1..1024    : x f32 [2048][1024] -> xbf bf16 (2 token rows / block)
//   blocks 1025..5120 : W f32 [e][k][n] -> wbf bf16 transposed [e][n][k]
// ---------------------------------------------------------------------------
__global__ __launch_bounds__(256) void prep(
    const float* __restrict__ x,
    const int*   __restrict__ gate_idx,
    const float* __restrict__ W,
    unsigned short* __restrict__ xbf,
    unsigned short* __restrict__ wbf,
    int* __restrict__ counts, int* __restrict__ offsets, int* __restrict__ list)
{
    __shared__ __align__(16) unsigned short sT[64][72];   // 9216 B (also routing scratch)
    const int bid = blockIdx.x;
    const int t   = threadIdx.x;

    if (bid == 0) {
        // ---- routing
        int* s_cnt = (int*)&sT[0][0];
        int* s_off = s_cnt + NEXPERT;
        if (t < NEXPERT) s_cnt[t] = 0;
        __syncthreads();
        for (int a = t; a < NASSIGN; a += 256)
            atomicAdd(&s_cnt[gate_idx[a]], 1);
        __syncthreads();
        if (t == 0) {
            int run = 0;
            for (int e = 0; e < NEXPERT; e++) { s_off[e] = run; run += s_cnt[e]; }
        }
        __syncthreads();
        if (t < NEXPERT) {
            counts[t]  = s_cnt[t];
            offsets[t] = s_off[t];
            s_cnt[t]   = s_off[t];            // reuse as cursor
        }
        __syncthreads();
        for (int a = t; a < NASSIGN; a += 256) {
            int e = gate_idx[a];
            list[atomicAdd(&s_cnt[e], 1)] = a;
        }
    } else if (bid <= T_TOKENS / 2) {
        // ---- x -> bf16 (2 rows per block)
        const int tr = (bid - 1) * 2 + (t >> 7);
        const int c  = (t & 127) * 8;
        const float4* p = (const float4*)(x + (size_t)tr * DMODEL + c);
        const float4 v0 = p[0], v1 = p[1];
        __align__(16) unsigned short cv[8];
        cv[0] = f2bf(v0.x); cv[1] = f2bf(v0.y); cv[2] = f2bf(v0.z); cv[3] = f2bf(v0.w);
        cv[4] = f2bf(v1.x); cv[5] = f2bf(v1.y); cv[6] = f2bf(v1.z); cv[7] = f2bf(v1.w);
        *(ushort8*)(xbf + (size_t)tr * DMODEL + c) = *(ushort8*)&cv[0];
    } else {
        // ---- W transpose 64x64 tile: [e][k][n] -> [e][n][k], float4 loads
        const int wb = bid - (T_TOKENS / 2 + 1);
        const int e  = wb >> 8;
        const int k0 = ((wb >> 4) & 15) * 64;
        const int n0 = (wb & 15) * 64;
        const int ks = t >> 4;          // k sub-row within group of 16
        const int nq = (t & 15) * 4;    // 4-wide n quad
        const float* srcbase = W + ((size_t)(e * DMODEL + k0 + ks)) * DMODEL + n0 + nq;
        #pragma unroll
        for (int c = 0; c < 4; c++) {
            const int k = c * 16 + ks;
            const float4 v = *(const float4*)(srcbase + (size_t)c * 16 * DMODEL);
            sT[nq + 0][k] = f2bf(v.x);
            sT[nq + 1][k] = f2bf(v.y);
            sT[nq + 2][k] = f2bf(v.z);
            sT[nq + 3][k] = f2bf(v.w);
        }
        __syncthreads();
        const int nr = t >> 2, kc = t & 3;
        ushort8 v0 = *(const ushort8*)&sT[nr][kc * 16];
        ushort8 v1 = *(const ushort8*)&sT[nr][kc * 16 + 8];
        unsigned short* dst = wbf + (size_t)(e * DMODEL + n0 + nr) * DMODEL + k0 + kc * 16;
        *(ushort8*)dst       = v0;
        *(ushort8*)(dst + 8) = v1;
    }
}

// ---------------------------------------------------------------------------
// Grouped GEMM, 64x128 tile, BK=64 (r6 structure — measured best). Pure
// global_load_lds staging with XOR chunk-swizzle; token rows gathered per-lane
// at the g2l SOURCE. 4 waves; wave w -> cols w*32..+32; per K-tile
// 2 kk x 4 mi x 2 ni MFMA. Epilogue: eo (bf16) = score*(acc + bias),
// exclusive slot per (a, col) — no atomics.
// ---------------------------------------------------------------------------
__global__ __launch_bounds__(256) void moe_gemm_bf(
    const unsigned short* __restrict__ xbf,   // [T][D] bf16
    const unsigned short* __restrict__ wbf,   // [E][n][k] bf16
    const float* __restrict__ bias,           // [E][D]
    const float* __restrict__ score,          // [T*TOPK]
    const int*   __restrict__ counts,
    const int*   __restrict__ offsets,
    const int*   __restrict__ list,
    unsigned short* __restrict__ eo)          // [NASSIGN][D] bf16
{
    const int e   = blockIdx.z;
    const int cnt = counts[e];
    const int m0  = blockIdx.y * GBM;
    if (m0 >= cnt) return;
    const int n0  = blockIdx.x * GBN;
    const int off = offsets[e];

    __shared__ __align__(16) unsigned short sA[GBM][GBK];   //  8 KB
    __shared__ __align__(16) unsigned short sB[GBN][GBK];   // 16 KB

    const int tid  = threadIdx.x;
    const int srow = tid >> 3;      // 0..31
    const int pch  = tid & 7;       // physical 16B chunk

    // A sources: rows srow, srow+32 of the m-tile, gathered via list
    const int ar0 = srow, ar1 = srow + 32;
    const int gm0 = m0 + ar0, gm1 = m0 + ar1;
    const int tok0 = (gm0 < cnt) ? (list[off + gm0] >> 1) : 0;
    const int tok1 = (gm1 < cnt) ? (list[off + gm1] >> 1) : 0;
    const unsigned short* asrc0 = xbf + (size_t)tok0 * DMODEL + (pch ^ (ar0 & 7)) * 8;
    const unsigned short* asrc1 = xbf + (size_t)tok1 * DMODEL + (pch ^ (ar1 & 7)) * 8;

    // B sources: rows srow + i*32 of the n-tile
    const unsigned short* wbbase = wbf + (size_t)e * DMODEL * DMODEL;
    const unsigned short* bsrc[4];
    #pragma unroll
    for (int i = 0; i < 4; i++) {
        const int row = i * 32 + srow;
        bsrc[i] = wbbase + (size_t)(n0 + row) * DMODEL + (pch ^ (row & 7)) * 8;
    }

    char* lA = (char*)&sA[0][0] + tid * 16;
    char* lB = (char*)&sB[0][0] + tid * 16;

    const int wave = tid >> 6;
    const int lane = tid & 63;
    const int wn   = wave * 32;
    const int fr   = lane & 15;
    const int quad = lane >> 4;

    floatx4 acc[4][2] = {};

    for (int k0 = 0; k0 < DMODEL; k0 += GBK) {
        g2l16(asrc0 + k0, lA);
        g2l16(asrc1 + k0, lA + 4096);
        g2l16(bsrc[0] + k0, lB);
        g2l16(bsrc[1] + k0, lB + 4096);
        g2l16(bsrc[2] + k0, lB + 8192);
        g2l16(bsrc[3] + k0, lB + 12288);
        __syncthreads();   // compiler drains vmcnt before barrier

        #pragma unroll
        for (int kk = 0; kk < 2; kk++) {
            const int cc = (kk * 4 + quad) ^ (fr & 7);   // swizzled chunk
            short8 af[4], bf[2];
            #pragma unroll
            for (int mi = 0; mi < 4; mi++)
                af[mi] = *(const short8*)&sA[mi * 16 + fr][cc * 8];
            #pragma unroll
            for (int ni = 0; ni < 2; ni++)
                bf[ni] = *(const short8*)&sB[wn + ni * 16 + fr][cc * 8];
            #pragma unroll
            for (int mi = 0; mi < 4; mi++)
                #pragma unroll
                for (int ni = 0; ni < 2; ni++)
                    acc[mi][ni] = __builtin_amdgcn_mfma_f32_16x16x32_bf16(
                        af[mi], bf[ni], acc[mi][ni], 0, 0, 0);
        }
        __syncthreads();
    }

    // epilogue: C/D layout col = lane&15, row = quad*4 + r  [m89]
    const int colA = n0 + wn + fr;
    const int colB = colA + 16;
    const float bv0 = bias[e * DMODEL + colA];
    const float bv1 = bias[e * DMODEL + colB];
    #pragma unroll
    for (int mi = 0; mi < 4; mi++) {
        const int rb = mi * 16 + quad * 4;
        #pragma unroll
        for (int r = 0; r < 4; r++) {
            const int gm = m0 + rb + r;
            if (gm >= cnt) continue;
            const int a = list[off + gm];
            const float s = score[a];
            unsigned short* row = eo + (size_t)a * DMODEL;
            row[colA] = f2bf(s * (acc[mi][0][r] + bv0));
            row[colB] = f2bf(s * (acc[mi][1][r] + bv1));
        }
    }
}

// ---------------------------------------------------------------------------
// Combine: out[t] = eo[2t] + eo[2t+1]  (bf16 in, f32 out; score&bias applied)
// ---------------------------------------------------------------------------
__global__ __launch_bounds__(256) void combine(const unsigned short* __restrict__ eo,
                                               float* __restrict__ out) {
    const int t = blockIdx.x;
    const int d = threadIdx.x * 4;
    const usv4 a = *(const usv4*)(eo + (size_t)(2 * t)     * DMODEL + d);
    const usv4 b = *(const usv4*)(eo + (size_t)(2 * t + 1) * DMODEL + d);
    *(float4*)(out + (size_t)t * DMODEL + d) =
        make_float4(bf2f(a.x) + bf2f(b.x), bf2f(a.y) + bf2f(b.y),
                    bf2f(a.z) + bf2f(b.z), bf2f(a.w) + bf2f(b.w));
}

// ---------------------------------------------------------------------------
// Fallback (ws too small): routing + inline-conversion GEMM with atomics.
// ---------------------------------------------------------------------------
__global__ void build_routing(const int* __restrict__ gate_idx,
                              int* __restrict__ counts,
                              int* __restrict__ offsets,
                              int* __restrict__ list) {
    __shared__ int s_cnt[NEXPERT];
    __shared__ int s_off[NEXPERT];
    const int tid = threadIdx.x;
    if (tid < NEXPERT) s_cnt[tid] = 0;
    __syncthreads();
    for (int a = tid; a < NASSIGN; a += blockDim.x)
        atomicAdd(&s_cnt[gate_idx[a]], 1);
    __syncthreads();
    if (tid == 0) {
        int run = 0;
        for (int e = 0; e < NEXPERT; e++) { s_off[e] = run; run += s_cnt[e]; }
    }
    __syncthreads();
    if (tid < NEXPERT) {
        counts[tid]  = s_cnt[tid];
        offsets[tid] = s_off[tid];
        s_cnt[tid]   = s_off[tid];
    }
    __syncthreads();
    for (int a = tid; a < NASSIGN; a += blockDim.x) {
        int e = gate_idx[a];
        int pos = atomicAdd(&s_cnt[e], 1);
        list[pos] = a;
    }
}

#define LDSK 72
__global__ __launch_bounds__(256) void moe_gemm_inline(
    const float* __restrict__ x, const float* __restrict__ W,
    const float* __restrict__ bias, const float* __restrict__ score,
    const int* __restrict__ counts, const int* __restrict__ offsets,
    const int* __restrict__ list, float* __restrict__ dst)
{
    const int e   = blockIdx.z;
    const int cnt = counts[e];
    const int m0  = blockIdx.y * 64;
    if (m0 >= cnt) return;
    const int n0  = blockIdx.x * 64;
    const int off = offsets[e];

    __shared__ __align__(16) unsigned short sA[64][LDSK];
    __shared__ __align__(16) unsigned short sB[64][LDSK];

    const int tid = threadIdx.x;
    const int arow = tid >> 2, aq = tid & 3, acol = aq * 16;
    const bool avalid = (m0 + arow) < cnt;
    int atok = 0;
    if (avalid) atok = list[off + m0 + arow] >> 1;
    const float* xsrc = x + (size_t)atok * DMODEL + acol;

    const int bk = tid >> 2, bng = tid & 3, bn = bng * 16, rot = tid & 15;
    const float* wsrc = W + (size_t)(e * DMODEL + bk) * DMODEL + n0 + bn;

    const int wave = tid >> 6, lane = tid & 63;
    const int wn = wave * 16, fr = lane & 15, quad = lane >> 4;

    floatx4 acc[4] = {};

    for (int k0 = 0; k0 < DMODEL; k0 += 64) {
        {
            float4 v[4];
            if (avalid) {
                const float4* p = (const float4*)(xsrc + k0);
                v[0] = p[0]; v[1] = p[1]; v[2] = p[2]; v[3] = p[3];
            } else {
                v[0] = v[1] = v[2] = v[3] = make_float4(0.f, 0.f, 0.f, 0.f);
            }
            __align__(16) unsigned short cvt[16];
            #pragma unroll
            for (int i = 0; i < 4; i++) {
                cvt[4*i+0] = f2bf(v[i].x); cvt[4*i+1] = f2bf(v[i].y);
                cvt[4*i+2] = f2bf(v[i].z); cvt[4*i+3] = f2bf(v[i].w);
            }
            *(ushort8*)&sA[arow][acol]     = *(ushort8*)&cvt[0];
            *(ushort8*)&sA[arow][acol + 8] = *(ushort8*)&cvt[8];
        }
        {
            const float4* p = (const float4*)(wsrc + (size_t)k0 * DMODEL);
            float4 v[4];
            v[0] = p[0]; v[1] = p[1]; v[2] = p[2]; v[3] = p[3];
            unsigned short cvt[16];
            #pragma unroll
            for (int i = 0; i < 4; i++) {
                cvt[4*i+0] = f2bf(v[i].x); cvt[4*i+1] = f2bf(v[i].y);
                cvt[4*i+2] = f2bf(v[i].z); cvt[4*i+3] = f2bf(v[i].w);
            }
            #pragma unroll
            for (int i = 0; i < 16; i++) {
                int m = (i + rot) & 15;
                sB[bn + m][bk] = cvt[m];
            }
        }
        __syncthreads();
        #pragma unroll
        for (int kk = 0; kk < 2; kk++) {
            const int ko = kk * 32 + quad * 8;
            short8 af[4], bf;
            #pragma unroll
            for (int mi = 0; mi < 4; mi++)
                af[mi] = *(const short8*)&sA[mi * 16 + fr][ko];
            bf = *(const short8*)&sB[wn + fr][ko];
            #pragma unroll
            for (int mi = 0; mi < 4; mi++)
                acc[mi] = __builtin_amdgcn_mfma_f32_16x16x32_bf16(af[mi], bf, acc[mi], 0, 0, 0);
        }
        __syncthreads();
    }

    const int col = n0 + wn + fr;
    const float bv = bias[e * DMODEL + col];
    #pragma unroll
    for (int mi = 0; mi < 4; mi++) {
        const int rb = mi * 16 + quad * 4;
        #pragma unroll
        for (int r = 0; r < 4; r++) {
            const int gm = m0 + rb + r;
            if (gm >= cnt) continue;
            const int a = list[off + gm];
            atomicAdd(&dst[(size_t)(a >> 1) * DMODEL + col],
                      score[a] * (acc[mi][r] + bv));
        }
    }
}

extern "C" void kernel_launch(void* const* d_in, const int* in_sizes, int n_in,
                              void* d_out, int out_size, void* d_ws, size_t ws_size,
                              hipStream_t stream) {
    const float* x    = (const float*)d_in[0];   // [2048,1024] f32
    const int*   gidx = (const int*)d_in[1];     // [2048,2] int
    const float* gsc  = (const float*)d_in[2];   // [2048,2] f32
    const float* W    = (const float*)d_in[3];   // [16,1024,1024] f32
    const float* bias = (const float*)d_in[4];   // [16,1024] f32
    float* out = (float*)d_out;

    int* ws      = (int*)d_ws;
    int* counts  = ws;
    int* offsets = ws + 16;
    int* list    = ws + 32;

    const size_t eo_off  = 32 * 1024;
    const size_t eo_sz   = (size_t)NASSIGN * DMODEL * sizeof(unsigned short);      //  8 MB
    const size_t xbf_off = eo_off + eo_sz;
    const size_t xbf_sz  = (size_t)T_TOKENS * DMODEL * sizeof(unsigned short);     //  4 MB
    const size_t wbf_off = xbf_off + xbf_sz;
    const size_t wbf_sz  = (size_t)NEXPERT * DMODEL * DMODEL * sizeof(unsigned short); // 32 MB
    const size_t need_full = wbf_off + wbf_sz;

    unsigned short* eo  = (unsigned short*)((char*)d_ws + eo_off);
    unsigned short* xbf = (unsigned short*)((char*)d_ws + xbf_off);
    unsigned short* wbf = (unsigned short*)((char*)d_ws + wbf_off);

    if (ws_size >= need_full) {
        prep<<<1 + T_TOKENS / 2 + NEXPERT * 16 * 16, 256, 0, stream>>>(
            x, gidx, W, xbf, wbf, counts, offsets, list);
        dim3 grid(DMODEL / GBN, 512 / GBM, NEXPERT);   // y covers cnt <= 512
        moe_gemm_bf<<<grid, 256, 0, stream>>>(xbf, wbf, bias, gsc,
                                              counts, offsets, list, eo);
        combine<<<T_TOKENS, 256, 0, stream>>>(eo, out);
    } else {
        build_routing<<<1, 256, 0, stream>>>(gidx, counts, offsets, list);
        hipMemsetAsync(d_out, 0, (size_t)T_TOKENS * DMODEL * sizeof(float), stream);
        dim3 grid(DMODEL / 64, 512 / 64, NEXPERT);
        moe_gemm_inline<<<grid, 256, 0, stream>>>(x, W, bias, gsc,
                                                  counts, offsets, list, out);
    }
}